// Round 5
// baseline (190.425 us; speedup 1.0000x reference)
//
#include <hip/hip_runtime.h>
#include <hip/hip_bf16.h>

// Problem constants: B=64, Cin=3, H=W=64, O=16, k=7, fh=fw=58
#define O_ 16
#define CIN 3
#define NTAP 49
#define NBUCK 256
#define NCLASS 169            // 13 row-classes x 13 col-classes
#define CL_INT 84             // 6*13+6 = interior class
#define BSCALE 512.0f         // 1/bucket_width; value range [-0.25, 0.25)
#define BOFF 0.25f

// output geometry
#define SEG 10092u            // fh*fh*Cin
#define OSEG 161472u          // O*SEG
#define OUT1 10334208u        // B*OSEG
#define NOUT 31002624u        // 3*OUT1

// scratch tables live in the TAIL of d_out (fill overwrites them last).
// floats, relative to tail base:
#define TAIL_BASE (NOUT - 524288u)   // 30,478,336
#define T_HIST 0u                     // [3][169][256][2]  = 259,584 floats
#define T_P    260096u                // [3][169][257]     = 130,299 floats
#define T_S    390400u                // [3][169][257]     = 130,299 floats

typedef float v4f __attribute__((ext_vector_type(4)));

// ---------------------------------------------------------------------------
// 1) histogram: per (channel, pixel-class) count+sum buckets.
//    class rc: 0..5 = rows 0..5, 6 = rows 6..57, 7..12 = rows 58..63 (py-51).
//    Interior class (rc==6 && cc==6) aggregated in LDS, flushed once.
// ---------------------------------------------------------------------------
__global__ __launch_bounds__(256) void hist_kernel(
    const float* __restrict__ x, float* __restrict__ tail)
{
    __shared__ float sH[NBUCK * 2];
    for (int i = threadIdx.x; i < NBUCK * 2; i += 256) sH[i] = 0.f;
    __syncthreads();

    const int plane = blockIdx.x >> 1;           // 0..191
    const int half  = blockIdx.x & 1;
    const int c     = plane % 3;
    const float4* src = (const float4*)(x + plane * 4096);
    float* hist = tail + T_HIST + (unsigned)c * (NCLASS * NBUCK * 2);

#pragma unroll
    for (int j = 0; j < 2; ++j) {
        int f4 = half * 512 + threadIdx.x + j * 256;   // coalesced float4
        float4 val = src[f4];
        int pix0 = f4 * 4;
        float vv[4] = {val.x, val.y, val.z, val.w};
#pragma unroll
        for (int e = 0; e < 4; ++e) {
            int idx = pix0 + e;
            int py = idx >> 6, px = idx & 63;
            int rc = (py < 6) ? py : ((py >= 58) ? py - 51 : 6);
            int cc = (px < 6) ? px : ((px >= 58) ? px - 51 : 6);
            float v = vv[e];
            int b = (int)((v + BOFF) * BSCALE);
            b = min(max(b, 0), NBUCK - 1);
            if (rc == 6 && cc == 6) {
                atomicAdd(&sH[b * 2],     1.f);
                atomicAdd(&sH[b * 2 + 1], v);
            } else {
                int cl = rc * 13 + cc;
                atomicAdd(&hist[(cl * NBUCK + b) * 2],     1.f);
                atomicAdd(&hist[(cl * NBUCK + b) * 2 + 1], v);
            }
        }
    }
    __syncthreads();
    for (int b = threadIdx.x; b < NBUCK; b += 256) {
        float cn = sH[b * 2], sm = sH[b * 2 + 1];
        if (cn != 0.f) {
            atomicAdd(&hist[(CL_INT * NBUCK + b) * 2],     cn);
            atomicAdd(&hist[(CL_INT * NBUCK + b) * 2 + 1], sm);
        }
    }
}

// ---------------------------------------------------------------------------
// 2) prefix: one wave per (c,class): exclusive prefix of (cnt,sum) + totals.
// ---------------------------------------------------------------------------
__global__ __launch_bounds__(64) void prefix_kernel(float* __restrict__ tail)
{
    const int id = blockIdx.x;                     // c*169+cl, 0..506
    const float* h = tail + T_HIST + (unsigned)id * (NBUCK * 2);
    float* P = tail + T_P + (unsigned)id * 257;
    float* S = tail + T_S + (unsigned)id * 257;
    const int lane = threadIdx.x;
    float cc = 0.f, cs = 0.f;
#pragma unroll
    for (int ch = 0; ch < 4; ++ch) {
        int b = ch * 64 + lane;
        float xc = h[b * 2], xs = h[b * 2 + 1];
        float ic = xc, is = xs;
#pragma unroll
        for (int off = 1; off < 64; off <<= 1) {
            float tc = __shfl_up(ic, off);
            float ts = __shfl_up(is, off);
            if (lane >= off) { ic += tc; is += ts; }
        }
        P[b] = cc + ic - xc;                       // exclusive
        S[b] = cs + is - xs;
        cc += __shfl(ic, 63);
        cs += __shfl(is, 63);
    }
    if (lane == 0) { P[256] = cc; S[256] = cs; }
}

// ---------------------------------------------------------------------------
// 3) query: 4704 threads, one per (hm,o,c,dy,dx).
//    Valid classes for tap (dy,dx): rc in [dy,dy+6], cc in [dx,dx+6].
//    HitStyle(k) per class = k*P[b] - S[b] + cb*relu(k - mean_b).
//    hit  -> gsum[o]    += sum HitStyle
//    miss -> gsum[16+o] += (Ts - k*Tn) + sum HitStyle
// ---------------------------------------------------------------------------
__global__ __launch_bounds__(256) void query_kernel(
    const float* __restrict__ Kh, const float* __restrict__ Km,
    const float* __restrict__ tail, float* __restrict__ gsum)
{
    int tid = blockIdx.x * 256 + threadIdx.x;
    if (tid >= 4704) return;
    int hm = tid / 2352; int r = tid - hm * 2352;
    int o = r / 147;     int r2 = r - o * 147;
    int c = r2 / 49;     int t = r2 - c * 49;
    int dy = t / 7,      dx = t - dy * 7;
    float k = (hm ? Km : Kh)[(o * 3 + c) * 49 + t];
    int b = (int)((k + BOFF) * BSCALE);
    b = min(max(b, 0), NBUCK - 1);

    float acc = 0.f, Tn = 0.f, Ts = 0.f;
    for (int i = 0; i < 7; ++i) {
        int rc = dy + i;
        for (int j = 0; j < 7; ++j) {
            int cl = rc * 13 + (dx + j);
            const float* P = tail + T_P + (unsigned)(c * NCLASS + cl) * 257;
            const float* S = tail + T_S + (unsigned)(c * NCLASS + cl) * 257;
            float p0 = P[b], p1 = P[b + 1];
            float s0 = S[b], s1 = S[b + 1];
            acc += k * p0 - s0;                    // pixels strictly below k's bucket
            float cb = p1 - p0;                    // k's own bucket: mean approx
            if (cb > 0.f) acc += cb * fmaxf(k - (s1 - s0) / cb, 0.f);
            Tn += P[256];
            Ts += S[256];
        }
    }
    if (hm == 0) atomicAdd(&gsum[o], acc);
    else         atomicAdd(&gsum[16 + o], (Ts - k * Tn) + acc);
}

// ---------------------------------------------------------------------------
// 4) fill: s_hit = -gsum[o], s_miss = gsum[16+o]; broadcast-fill 124 MB.
// ---------------------------------------------------------------------------
__global__ __launch_bounds__(256) void fill_kernel(
    const float* __restrict__ gsum, v4f* __restrict__ out, unsigned n4)
{
    __shared__ float sv[48];
    if (threadIdx.x < 48) {
        int o = threadIdx.x & 15, grp = threadIdx.x >> 4;
        float h = -gsum[o];
        float m = gsum[16 + o];
        sv[threadIdx.x] = (grp == 0) ? (h - m) : ((grp == 1) ? h : m);
    }
    __syncthreads();
    unsigned stride = gridDim.x * blockDim.x;
    for (unsigned i = blockIdx.x * blockDim.x + threadIdx.x; i < n4; i += stride) {
        unsigned f = i * 4u;
        unsigned w   = f / OUT1;
        unsigned rem = f - w * OUT1;
        unsigned o   = (rem % OSEG) / SEG;
        float val = sv[w * 16 + o];
        v4f pk = {val, val, val, val};
        __builtin_nontemporal_store(pk, &out[i]);
    }
}

extern "C" void kernel_launch(void* const* d_in, const int* in_sizes, int n_in,
                              void* d_out, int out_size, void* d_ws, size_t ws_size,
                              hipStream_t stream)
{
    const float* x  = (const float*)d_in[0];
    const float* Kh = (const float*)d_in[1];
    const float* Km = (const float*)d_in[2];
    float* out  = (float*)d_out;
    float* tail = out + TAIL_BASE;     // scratch tables in d_out tail
    float* gsum = (float*)d_ws;        // 32 floats

    hipMemsetAsync(tail + T_HIST, 0, (size_t)259584 * sizeof(float), stream);
    hipMemsetAsync(gsum, 0, 32 * sizeof(float), stream);

    hist_kernel  <<<384, 256, 0, stream>>>(x, tail);
    prefix_kernel<<<507,  64, 0, stream>>>(tail);
    query_kernel <<<19,  256, 0, stream>>>(Kh, Km, tail, gsum);
    fill_kernel  <<<4096, 256, 0, stream>>>(gsum, (v4f*)out, NOUT / 4u);
}

// Round 6
// 102.070 us; speedup vs baseline: 1.8656x; 1.8656x over previous
//
#include <hip/hip_runtime.h>
#include <hip/hip_bf16.h>

// Problem constants: B=64, Cin=3, H=W=64, O=16, k=7, fh=fw=58
#define O_ 16
#define CIN 3
#define NBUCK 512
#define WB 0.0009765625f       // bucket width = 1/1024, range [-0.25, 0.25)
#define NCLASS 169             // 13 row-classes x 13 col-classes
#define CL_INT 84              // interior class (rc=6, cc=6)

// output geometry
#define SEG 10092u             // fh*fh*Cin
#define OSEG 161472u           // O*SEG
#define OUT1 10334208u         // B*OSEG
#define NOUT 31002624u         // 3*OUT1

// scratch in the TAIL of d_out (fill overwrites last). float offsets:
#define TAIL_BASE (NOUT - 786432u)      // 30,216,192
#define T_PART  0u                       // 192 slots x 1360: [0..512) int-hist, [512..1357) scalars 169x5
#define T_BHIST 261120u                  // 3*169*512 count hist (atomics for boundary classes)
#define T_SCAL  520704u                  // 3*169*5 reduced scalars
#define T_TTAB  523240u                  // 3*169*513 T tables

typedef float v4f __attribute__((ext_vector_type(4)));

// ---------------------------------------------------------------------------
// 1) build: one block per (b,c) plane. LDS: interior in-range count hist +
//    per-class scalars (cntL,sumL,cntR,sumR,sumIn). Boundary in-range counts
//    go straight to global atomics (spread over 258K addresses -> ~0 contention).
//    Interior hist + scalars -> private per-plane slot (plain stores).
// ---------------------------------------------------------------------------
__global__ __launch_bounds__(256) void build_kernel(
    const float* __restrict__ x, float* __restrict__ tail)
{
    __shared__ float sH[NBUCK];
    __shared__ float sS[NCLASS * 5];
    for (int i = threadIdx.x; i < NBUCK; i += 256) sH[i] = 0.f;
    for (int i = threadIdx.x; i < NCLASS * 5; i += 256) sS[i] = 0.f;
    __syncthreads();

    const int plane = blockIdx.x;
    const int c     = plane % 3;
    const float4* src = (const float4*)(x + plane * 4096);
    float* bhist = tail + T_BHIST + (unsigned)c * (NCLASS * NBUCK);

#pragma unroll
    for (int it = 0; it < 4; ++it) {
        int f4 = it * 256 + threadIdx.x;
        float4 val = src[f4];
        float vv[4] = {val.x, val.y, val.z, val.w};
        int pix0 = f4 * 4;
#pragma unroll
        for (int e = 0; e < 4; ++e) {
            int idx = pix0 + e;
            int py = idx >> 6, px = idx & 63;
            int rc = (py < 6) ? py : ((py >= 58) ? py - 51 : 6);
            int cc = (px < 6) ? px : ((px >= 58) ? px - 51 : 6);
            int cl = rc * 13 + cc;
            float v = vv[e];
            if (v < -0.25f) {
                atomicAdd(&sS[cl * 5 + 0], 1.f);
                atomicAdd(&sS[cl * 5 + 1], v);
            } else if (v >= 0.25f) {
                atomicAdd(&sS[cl * 5 + 2], 1.f);
                atomicAdd(&sS[cl * 5 + 3], v);
            } else {
                atomicAdd(&sS[cl * 5 + 4], v);
                int b = (int)((v + 0.25f) * 1024.f);
                b = min(max(b, 0), NBUCK - 1);
                if (cl == CL_INT) atomicAdd(&sH[b], 1.f);
                else              atomicAdd(&bhist[cl * NBUCK + b], 1.f);
            }
        }
    }
    __syncthreads();
    float* part = tail + T_PART + (unsigned)plane * 1360u;
    for (int i = threadIdx.x; i < NBUCK; i += 256) part[i] = sH[i];
    for (int i = threadIdx.x; i < NCLASS * 5; i += 256) part[NBUCK + i] = sS[i];
}

// ---------------------------------------------------------------------------
// 2) reduce: fold 64 plane-slots per channel into interior hist + scalars.
//    items: 3*512 interior cells + 3*845 scalar cells = 4071.
// ---------------------------------------------------------------------------
__global__ __launch_bounds__(256) void reduce_kernel(float* __restrict__ tail)
{
    int tid = blockIdx.x * 256 + threadIdx.x;
    if (tid < 3 * NBUCK) {
        int c = tid / NBUCK, b = tid % NBUCK;
        float s = 0.f;
        for (int i = 0; i < 64; ++i)
            s += tail[T_PART + (unsigned)(3 * i + c) * 1360u + b];
        tail[T_BHIST + ((unsigned)c * NCLASS + CL_INT) * NBUCK + b] = s;
    } else if (tid < 3 * NBUCK + 3 * NCLASS * 5) {
        int j = tid - 3 * NBUCK;
        int c = j / (NCLASS * 5), r = j % (NCLASS * 5);
        float s = 0.f;
        for (int i = 0; i < 64; ++i)
            s += tail[T_PART + (unsigned)(3 * i + c) * 1360u + NBUCK + r];
        tail[T_SCAL + (unsigned)c * (NCLASS * 5) + r] = s;
    }
}

// ---------------------------------------------------------------------------
// 3) tbuild: per (c,class) wave: T[j] = sum_b cnt_b * |center_j - center_b|
//    via double prefix scan:  T[j] = T0 + w*(2*Q[j] - j*N),  Q[j]=sum_{i<j}P[i].
// ---------------------------------------------------------------------------
__global__ __launch_bounds__(64) void tbuild_kernel(float* __restrict__ tail)
{
    __shared__ float P[NBUCK];
    const int id = blockIdx.x;                   // c*169+cl
    const float* hist = tail + T_BHIST + (unsigned)id * NBUCK;
    float* T = tail + T_TTAB + (unsigned)id * 513u;
    const int lane = threadIdx.x;

    float carry = 0.f, t0acc = 0.f;
#pragma unroll
    for (int ch = 0; ch < 8; ++ch) {
        int b = ch * 64 + lane;
        float cnt = hist[b];
        t0acc += (float)b * cnt;
        float ic = cnt;
#pragma unroll
        for (int off = 1; off < 64; off <<= 1) {
            float tc = __shfl_up(ic, off);
            if (lane >= off) ic += tc;
        }
        P[b] = carry + ic;
        carry += __shfl(ic, 63);
    }
    const float N = carry;                       // total in-range count
#pragma unroll
    for (int off = 32; off > 0; off >>= 1) t0acc += __shfl_down(t0acc, off);
    const float T0 = WB * __shfl(t0acc, 0);
    __syncthreads();

    float carryQ = 0.f;
#pragma unroll
    for (int ch = 0; ch < 8; ++ch) {
        int b = ch * 64 + lane;
        float pv = P[b];
        float ic = pv;
#pragma unroll
        for (int off = 1; off < 64; off <<= 1) {
            float tc = __shfl_up(ic, off);
            if (lane >= off) ic += tc;
        }
        float Q = carryQ + ic - pv;              // exclusive
        T[b] = T0 + WB * (2.f * Q - (float)b * N);
        carryQ += __shfl(ic, 63);
    }
    if (lane == 0) T[512] = T0 + WB * (2.f * carryQ - 512.f * N);
}

// ---------------------------------------------------------------------------
// 4) query: 4704 threads, one per (hm,o,c,dy,dx). Per valid class:
//    abs  += lerp(T,k) + (k*cntL - sumL) + (sumR - k*cntR)
//    lin  += k*Ntot_cl - (sumL + sumR + sumIn)
//    hit:  sum relu(k-v) = 0.5*(lin+abs);  miss: sum relu(v-k) = 0.5*(abs-lin)
// ---------------------------------------------------------------------------
__global__ __launch_bounds__(256) void query_kernel(
    const float* __restrict__ Kh, const float* __restrict__ Km,
    const float* __restrict__ tail, float* __restrict__ gsum)
{
    int tid = blockIdx.x * 256 + threadIdx.x;
    if (tid >= 4704) return;
    int hm = tid / 2352; int r = tid - hm * 2352;
    int o = r / 147;     int r2 = r - o * 147;
    int c = r2 / 49;     int t = r2 - c * 49;
    int dy = t / 7,      dx = t - dy * 7;
    float k = (hm ? Km : Kh)[(o * 3 + c) * 49 + t];
    float fb = (k + 0.25f) * 1024.f;
    int j = min(max((int)fb, 0), NBUCK - 1);
    float frac = fb - (float)j;

    float accA = 0.f, accL = 0.f;
    for (int i = 0; i < 7; ++i) {
        int rc = dy + i;
        float nr = (rc == 6) ? 52.f : 1.f;
        for (int jj = 0; jj < 7; ++jj) {
            int cc = dx + jj;
            float nc = (cc == 6) ? 52.f : 1.f;
            int id = c * NCLASS + rc * 13 + cc;
            const float* T  = tail + T_TTAB + (unsigned)id * 513u;
            const float* S5 = tail + T_SCAL + (unsigned)id * 5u;
            float t0 = T[j], t1 = T[j + 1];
            float A = t0 + frac * (t1 - t0);
            float cntL = S5[0], sumL = S5[1], cntR = S5[2], sumR = S5[3], sumIn = S5[4];
            accA += A + (k * cntL - sumL) + (sumR - k * cntR);
            accL += k * (nr * nc * 64.f) - (sumL + sumR + sumIn);
        }
    }
    if (hm == 0) atomicAdd(&gsum[o],      0.5f * (accL + accA));
    else         atomicAdd(&gsum[16 + o], 0.5f * (accA - accL));
}

// ---------------------------------------------------------------------------
// 5) fill: s_hit = -gsum[o], s_miss = gsum[16+o]; broadcast-fill 124 MB.
// ---------------------------------------------------------------------------
__global__ __launch_bounds__(256) void fill_kernel(
    const float* __restrict__ gsum, v4f* __restrict__ out, unsigned n4)
{
    __shared__ float sv[48];
    if (threadIdx.x < 48) {
        int o = threadIdx.x & 15, grp = threadIdx.x >> 4;
        float h = -gsum[o];
        float m = gsum[16 + o];
        sv[threadIdx.x] = (grp == 0) ? (h - m) : ((grp == 1) ? h : m);
    }
    __syncthreads();
    unsigned stride = gridDim.x * blockDim.x;
    for (unsigned i = blockIdx.x * blockDim.x + threadIdx.x; i < n4; i += stride) {
        unsigned f = i * 4u;
        unsigned w   = f / OUT1;
        unsigned rem = f - w * OUT1;
        unsigned o   = (rem % OSEG) / SEG;
        float val = sv[w * 16 + o];
        v4f pk = {val, val, val, val};
        __builtin_nontemporal_store(pk, &out[i]);
    }
}

extern "C" void kernel_launch(void* const* d_in, const int* in_sizes, int n_in,
                              void* d_out, int out_size, void* d_ws, size_t ws_size,
                              hipStream_t stream)
{
    const float* x  = (const float*)d_in[0];
    const float* Kh = (const float*)d_in[1];
    const float* Km = (const float*)d_in[2];
    float* out  = (float*)d_out;
    float* tail = out + TAIL_BASE;
    float* gsum = (float*)d_ws;        // 32 floats

    hipMemsetAsync(tail + T_BHIST, 0, (size_t)(3 * NCLASS * NBUCK) * sizeof(float), stream);
    hipMemsetAsync(gsum, 0, 32 * sizeof(float), stream);

    build_kernel <<<192, 256, 0, stream>>>(x, tail);
    reduce_kernel<<<16, 256, 0, stream>>>(tail);
    tbuild_kernel<<<507, 64, 0, stream>>>(tail);
    query_kernel <<<19, 256, 0, stream>>>(Kh, Km, tail, gsum);
    fill_kernel  <<<4096, 256, 0, stream>>>(gsum, (v4f*)out, NOUT / 4u);
}